// Round 9
// baseline (315.677 us; speedup 1.0000x reference)
//
#include <hip/hip_runtime.h>
#include <hip/hip_bf16.h>
#include <hip/hip_fp8.h>
#include <stdint.h>

#define NFEAT 32768
#define BATCH 1024
#define DK 64
#define DV 64
#define DD 4096
#define KSEL 32
#define CAND_CAP 512
#define CAND_TARGET 128

using bf16 = __bf16;
using bf16x8 = __attribute__((ext_vector_type(8))) __bf16;
using f32x4 = __attribute__((ext_vector_type(4))) float;
using f32x16 = __attribute__((ext_vector_type(16))) float;
using i32x4 = __attribute__((ext_vector_type(4))) int;
using i32x8 = __attribute__((ext_vector_type(8))) int;

__device__ __forceinline__ void gload_lds16(const void* g, void* l) {
  __builtin_amdgcn_global_load_lds((const __attribute__((address_space(1))) void*)g,
                                   (__attribute__((address_space(3))) void*)l,
                                   16, 0, 0);
}

__device__ inline unsigned mono16(unsigned u) {
  return (u & 0x8000u) ? ((~u) & 0xFFFFu) : (u | 0x8000u);
}

// ---------------- x -> fp8 e4m3 ----------------
__global__ void k_convert_x(const float* __restrict__ x, unsigned char* __restrict__ xb, int n) {
  int i = (blockIdx.x * blockDim.x + threadIdx.x) * 16;
  if (i >= n) return;
  union { unsigned char b[16]; uint4 u; } o;
#pragma unroll
  for (int j = 0; j < 16; j += 4) {
    float4 v = *reinterpret_cast<const float4*>(x + i + j);
    o.b[j + 0] = __hip_fp8_e4m3(v.x).__x;
    o.b[j + 1] = __hip_fp8_e4m3(v.y).__x;
    o.b[j + 2] = __hip_fp8_e4m3(v.z).__x;
    o.b[j + 3] = __hip_fp8_e4m3(v.w).__x;
  }
  *reinterpret_cast<uint4*>(xb + i) = o.u;
}

// ---------------- M_enc fp8: 16 * V_enc[i][k] * W_enc[i][v] (scale undone in epilogue) ----------------
__global__ void k_build_menc(const float* __restrict__ Venc, const float* __restrict__ Wenc,
                             unsigned char* __restrict__ Menc) {
  int i = blockIdx.x;
  int t = threadIdx.x;
  int k = t >> 2;
  int vb = (t & 3) << 4;
  float vk = 16.0f * Venc[i * DK + k];
  const float* wrow = Wenc + i * DV + vb;
  union { unsigned char b[16]; uint4 u; } o;
#pragma unroll
  for (int j = 0; j < 16; j += 4) {
    float4 w = *reinterpret_cast<const float4*>(wrow + j);
    o.b[j + 0] = __hip_fp8_e4m3(vk * w.x).__x;
    o.b[j + 1] = __hip_fp8_e4m3(vk * w.y).__x;
    o.b[j + 2] = __hip_fp8_e4m3(vk * w.z).__x;
    o.b[j + 3] = __hip_fp8_e4m3(vk * w.w).__x;
  }
  *reinterpret_cast<uint4*>(Menc + (size_t)i * DD + (t << 4)) = o.u;
}

// ---------------- GEMM: pre = bf16((x8 @ Menc8^T)/16 + b_enc), MX-fp8 MFMA ----------------
// 256x256 tile, BK=128 bytes, 8 waves (2M x 4N), double-buffered LDS, snake schedule
// (identical barrier/vmcnt proof as rounds 6-8). FRAGMENT-MAJOR LDS layout:
// chunk (b32,kg) = 1 KiB holding rows b32*32+(l&31), k-bytes kg*32+(l>>5)*16 at
// LDS pos l*16. ds_read: 32 consecutive 16B slots per half-wave => 0 bank conflicts.
#define BM 256
#define BN 256
#define BKB 128               // K-bytes (= fp8 elems) per tile
#define NT (DD / BKB)         // 32 K-tiles
#define ABUF 32768            // 32 chunks
#define BUFSZ 65536           // A + B per K-tile
#define GEMM_LDS (2 * BUFSZ)  // 128 KiB

// chunk c: b32 = c>>2 (32-row block), kg = c&3 (32-byte k-group)
__device__ __forceinline__ void stage_chunk(const unsigned char* __restrict__ G, size_t rowbase,
                                            int kb0, int c, int lane, char* dstbase) {
  int b32 = c >> 2, kg = c & 3;
  const unsigned char* src = G + (rowbase + (size_t)(b32 * 32 + (lane & 31))) * DD + kb0 +
                             kg * 32 + ((lane >> 5) << 4);
  gload_lds16(src, dstbase + c * 1024);
}

__device__ __forceinline__ i32x8 frag_ld8(const char* base, int chunk, int lane) {
  const char* p = base + chunk * 1024 + (lane & 31) * 16;
  i32x4 lo = *reinterpret_cast<const i32x4*>(p);
  i32x4 hi = *reinterpret_cast<const i32x4*>(p + 512);
  i32x8 r;
  r[0] = lo[0]; r[1] = lo[1]; r[2] = lo[2]; r[3] = lo[3];
  r[4] = hi[0]; r[5] = hi[1]; r[6] = hi[2]; r[7] = hi[3];
  return r;
}

// half-tile chunk maps (idx = wave*2 + j, 0..15)
// A-half h: mb32 in {0,1,4,5}+2h  (rows 0-63 & 128-191 for h=0) — same sets as proven schedule
__device__ __forceinline__ int chA(int half, int idx) {
  int g = idx >> 2, kg = idx & 3;
  int mb32 = (g & 1) + ((g >> 1) << 2) + half * 2;
  return mb32 * 4 + kg;
}
// B-half h: nb32 even/odd (first/second 32 of each 64-col band)
__device__ __forceinline__ int chB(int half, int idx) {
  int nb32 = ((idx >> 2) << 1) + half;
  return nb32 * 4 + (idx & 3);
}

// A frags for m-half H: mb32 = wr*4 + H*2 + mb; kg = kh*2 + (lane>>5)
#define LD_A(H)                                                                     \
  _Pragma("unroll") for (int mb = 0; mb < 2; ++mb)                                  \
  _Pragma("unroll") for (int kh = 0; kh < 2; ++kh)                                  \
    afr[mb][kh] = frag_ld8(cur, (wr * 4 + (H) * 2 + mb) * 4 + kh * 2 + (lane >> 5), lane);

// B frag for n-block H: nb32 = wc*2 + H
#define LD_B(H)                                                                     \
  _Pragma("unroll") for (int kh = 0; kh < 2; ++kh)                                  \
    bfr[(H)][kh] = frag_ld8(cur + ABUF, (wc * 2 + (H)) * 4 + kh * 2 + (lane >> 5), lane);

#define ST_A(HALF, KT)                                                              \
  stage_chunk(A, brow, (KT) * BKB, chA(HALF, wave * 2), lane, nxt);                 \
  stage_chunk(A, brow, (KT) * BKB, chA(HALF, wave * 2 + 1), lane, nxt);

#define ST_B(HALF, KT)                                                              \
  stage_chunk(Bt, bcol, (KT) * BKB, chB(HALF, wave * 2), lane, nxt + ABUF);         \
  stage_chunk(Bt, bcol, (KT) * BKB, chB(HALF, wave * 2 + 1), lane, nxt + ABUF);

#define MFMA_Q(MH, NB)                                                              \
  asm volatile("s_waitcnt lgkmcnt(0)" ::: "memory");                                \
  __builtin_amdgcn_sched_barrier(0);                                                \
  __builtin_amdgcn_s_setprio(1);                                                    \
  _Pragma("unroll") for (int mb = 0; mb < 2; ++mb)                                  \
  _Pragma("unroll") for (int kh = 0; kh < 2; ++kh)                                  \
    acc[(MH) * 2 + mb][NB] = __builtin_amdgcn_mfma_scale_f32_32x32x64_f8f6f4(       \
        afr[mb][kh], bfr[NB][kh], acc[(MH) * 2 + mb][NB], 0, 0, 0, 0x7F, 0, 0x7F);  \
  __builtin_amdgcn_s_setprio(0);

#define VMC(N) asm volatile("s_waitcnt vmcnt(" #N ")" ::: "memory");
#define LGKM0 asm volatile("s_waitcnt lgkmcnt(0)" ::: "memory");
#define BARR                                                                        \
  asm volatile("s_barrier" ::: "memory");                                           \
  __builtin_amdgcn_sched_barrier(0);

__global__ __launch_bounds__(512, 2)
void k_gemm(const unsigned char* __restrict__ A, const unsigned char* __restrict__ Bt,
            const float* __restrict__ benc, bf16* __restrict__ C) {
  extern __shared__ char lds[];
  int tid = threadIdx.x;
  int wave = tid >> 6;
  int lane = tid & 63;
  int wr = wave >> 2;          // 0..1, 128 rows each
  int wc = wave & 3;           // 0..3, 64 cols each

  // XCD-grouped bijective remap (512 blocks, 512%8==0)
  int d = blockIdx.x;                  // 0..511
  int lw = (d & 7) * 64 + (d >> 3);
  int q = lw >> 2;                     // col panel 0..127
  int p = lw & 3;                      // row block 0..3
  size_t brow = (size_t)p * BM;
  size_t bcol = (size_t)q * BN;

  f32x16 acc[4][2] = {};
  i32x8 afr[2][2];
  i32x8 bfr[2][2];

  // prologue: stage tile 0 (order B0,A0,B1,A1); publish B0,A0; barrier.
  {
    char* nxt = lds;
    ST_B(0, 0) ST_A(0, 0) ST_B(1, 0) ST_A(1, 0)
  }
  VMC(4)
  BARR

#pragma unroll 1
  for (int u = 0; u < NT - 1; ++u) {
    char* cur = lds + (u & 1) * BUFSZ;
    char* nxt = lds + ((u + 1) & 1) * BUFSZ;
    int k1 = u + 1;
    // q0: read A-h0, B-n0; stage B0(u+1); VMC(4) publishes B1(u) for q1
    LD_A(0) LD_B(0)
    ST_B(0, k1)
    VMC(4)
    BARR
    MFMA_Q(0, 0)
    // q1: read B-n1; stage A0(u+1); VMC(4) publishes A1(u) for q23
    LD_B(1)
    ST_A(0, k1)
    VMC(4)
    BARR
    MFMA_Q(0, 1)
    // q23: read A-h1; stage B1,A1(u+1); VMC(4) publishes B0,A0(u+1); lgkm drained pre-barrier
    LD_A(1)
    ST_B(1, k1) ST_A(1, k1)
    VMC(4)
    LGKM0
    BARR
    MFMA_Q(1, 1)
    MFMA_Q(1, 0)
  }

  // tail tile NT-1 (no staging); entry outstanding: B1(L),A1(L)
  {
    char* cur = lds + ((NT - 1) & 1) * BUFSZ;
    LD_A(0) LD_B(0)
    VMC(2)
    BARR
    MFMA_Q(0, 0)
    LD_B(1)
    VMC(0)
    BARR
    MFMA_Q(0, 1)
    LD_A(1)
    LGKM0
    BARR
    MFMA_Q(1, 1)
    MFMA_Q(1, 0)
  }

  // epilogue: 32x32 C/D layout col=lane&31, row=(reg&3)+8*(reg>>2)+4*(lane>>5); descale 1/16
#pragma unroll
  for (int nb = 0; nb < 2; ++nb) {
    size_t col = bcol + wc * 64 + nb * 32 + (lane & 31);
    float be = benc[col];
#pragma unroll
    for (int MB = 0; MB < 4; ++MB) {
      size_t row0 = brow + wr * 128 + MB * 32 + ((lane >> 5) << 2);
#pragma unroll
      for (int reg = 0; reg < 16; ++reg) {
        size_t row = row0 + (reg & 3) + ((reg >> 2) << 3);
        C[row * NFEAT + col] = (bf16)(acc[MB][nb][reg] * 0.0625f + be);
      }
    }
  }
}

// ---------------- candidate extraction from bf16 pre + zero coeffs row ----------------
__global__ void k_topk(const unsigned short* __restrict__ pre, int* __restrict__ cand_idx,
                       int* __restrict__ cand_cnt, float* __restrict__ coeffs) {
  __shared__ int hist[8192];   // 13-bit bins of 16-bit monotonic code
  __shared__ int csum[256];
  __shared__ int sBstar;
  __shared__ int scount;
  int b = blockIdx.x;
  int t = threadIdx.x;
  const unsigned short* row = pre + (size_t)b * NFEAT;
  for (int i = t; i < 8192; i += 256) hist[i] = 0;
  if (t == 0) scount = 0;
  __syncthreads();

  for (int i = (t << 3); i < NFEAT; i += 2048) {
    uint4 v = *reinterpret_cast<const uint4*>(row + i);
#pragma unroll
    for (int j = 0; j < 4; ++j) {
      unsigned w = (&v.x)[j];
      atomicAdd(&hist[mono16(w & 0xFFFFu) >> 3], 1);
      atomicAdd(&hist[mono16(w >> 16) >> 3], 1);
    }
  }
  __syncthreads();

  int s = 0;
  for (int i = 0; i < 32; ++i) s += hist[t * 32 + i];
  csum[t] = s;
  __syncthreads();
  int suff = 0;
  for (int j = t + 1; j < 256; ++j) suff += csum[j];
  if (suff < CAND_TARGET && suff + s >= CAND_TARGET) {
    int acc = suff;
    int bstar = t * 32;
    for (int i = 31; i >= 0; --i) {
      acc += hist[t * 32 + i];
      if (acc >= CAND_TARGET) { bstar = t * 32 + i; break; }
    }
    sBstar = bstar;
  }
  __syncthreads();
  int Bstar = sBstar;
  int* cidx = cand_idx + b * CAND_CAP;

  for (int i = (t << 3); i < NFEAT; i += 2048) {
    uint4 v = *reinterpret_cast<const uint4*>(row + i);
#pragma unroll
    for (int j = 0; j < 4; ++j) {
      unsigned w = (&v.x)[j];
      int b0 = (int)(mono16(w & 0xFFFFu) >> 3);
      int b1 = (int)(mono16(w >> 16) >> 3);
      if (b0 >= Bstar) { int p2 = atomicAdd(&scount, 1); if (p2 < CAND_CAP) cidx[p2] = i + j * 2; }
      if (b1 >= Bstar) { int p2 = atomicAdd(&scount, 1); if (p2 < CAND_CAP) cidx[p2] = i + j * 2 + 1; }
    }
  }
  __syncthreads();
  if (t == 0) cand_cnt[b] = (scount < CAND_CAP) ? scount : CAND_CAP;

  // zero this row of coeffs (pre lives in ws now; refine scatters after this kernel)
  float* crow = coeffs + (size_t)b * NFEAT;
  float4 z4 = {0.f, 0.f, 0.f, 0.f};
  for (int i = (t << 2); i < NFEAT; i += 1024)
    *reinterpret_cast<float4*>(crow + i) = z4;
}

// ---------------- fp32 refine + exact top-32 + scatter + decode + mse partial ----------------
__global__ void k_refine(const float* __restrict__ x,
                         const float* __restrict__ Venc,
                         const float* __restrict__ Wenc,
                         const float* __restrict__ benc,
                         const float* __restrict__ Vdec,
                         const float* __restrict__ Wdec,
                         const float* __restrict__ bias,
                         const int* __restrict__ cand_idx,
                         const int* __restrict__ cand_cnt,
                         float* __restrict__ recon,
                         float* __restrict__ coeffs,
                         float* __restrict__ msepart) {
  __shared__ float rval[CAND_CAP];
  __shared__ int ridx[CAND_CAP];
  __shared__ float selv[KSEL];
  __shared__ int seli[KSEL];
  __shared__ float Vd[KSEL][DK];
  __shared__ float Wd[KSEL][DV];
  __shared__ float red[256];

  int b = blockIdx.x;
  int t = threadIdx.x;
  int wave = t >> 6;
  int lane = t & 63;

  const float* xr = x + (size_t)b * DD;

  // per-lane register cache of x: xreg[kk] = x[b][kk][lane] (lane = v)
  float xreg[DK];
#pragma unroll
  for (int kk = 0; kk < DK; ++kk)
    xreg[kk] = xr[kk * DV + lane];

  int c = cand_cnt[b];
  if (c > CAND_CAP) c = CAND_CAP;
  for (int i = t; i < c; i += 256) ridx[i] = cand_idx[b * CAND_CAP + i];
  __syncthreads();

  // exact fp32 pre per candidate: V row via SGPR (uniform), x in regs, W coalesced
  for (int j = wave; j < c; j += 4) {
    int fi = __builtin_amdgcn_readfirstlane(ridx[j]);
    const float* vr = Venc + (size_t)fi * DK;
    float w = Wenc[(size_t)fi * DV + lane];
    float a0 = 0.f, a1 = 0.f, a2 = 0.f, a3 = 0.f;
#pragma unroll
    for (int kk = 0; kk < DK; kk += 4) {
      a0 = fmaf(xreg[kk + 0], vr[kk + 0], a0);
      a1 = fmaf(xreg[kk + 1], vr[kk + 1], a1);
      a2 = fmaf(xreg[kk + 2], vr[kk + 2], a2);
      a3 = fmaf(xreg[kk + 3], vr[kk + 3], a3);
    }
    float p2 = ((a0 + a1) + (a2 + a3)) * w;
#pragma unroll
    for (int off = 1; off < 64; off <<= 1) p2 += __shfl_xor(p2, off);
    if (lane == 0) rval[j] = p2 + benc[fi];
  }
  __syncthreads();

  // exact rank among candidates (tie-break: lower feature index first, matches np)
  for (int t2 = t; t2 < c; t2 += 256) {
    float v = rval[t2];
    int fi = ridx[t2];
    int rank = 0;
    for (int j = 0; j < c; ++j) {
      float vj = rval[j];
      if (vj > v || (vj == v && ridx[j] < fi)) ++rank;
    }
    if (rank < KSEL) { selv[rank] = v; seli[rank] = fi; }
  }
  __syncthreads();

  if (t < KSEL) {
    float v = fmaxf(selv[t], 0.f);
    selv[t] = v;
    coeffs[(size_t)b * NFEAT + seli[t]] = v;
  }
  __syncthreads();

  for (int i = t; i < KSEL * DK; i += 256) {
    int s = i >> 6, e = i & 63;
    Vd[s][e] = Vdec[(size_t)seli[s] * DK + e];
    Wd[s][e] = Wdec[(size_t)seli[s] * DV + e];
  }
  __syncthreads();

  // decode: thread owns 16 contiguous recon elems; Wd consumed as float4
  int k = t >> 2;
  int vb = (t & 3) << 4;
  float4 r4[4];
#pragma unroll
  for (int g = 0; g < 4; ++g)
    r4[g] = *reinterpret_cast<const float4*>(bias + k * DV + vb + g * 4);
#pragma unroll
  for (int s = 0; s < KSEL; ++s) {
    float a = selv[s] * Vd[s][k];
    const float4* wrow = reinterpret_cast<const float4*>(&Wd[s][vb]);
#pragma unroll
    for (int g = 0; g < 4; ++g) {
      float4 wv = wrow[g];
      r4[g].x = fmaf(a, wv.x, r4[g].x);
      r4[g].y = fmaf(a, wv.y, r4[g].y);
      r4[g].z = fmaf(a, wv.z, r4[g].z);
      r4[g].w = fmaf(a, wv.w, r4[g].w);
    }
  }
  float m = 0.f;
  float* ro = recon + (size_t)b * DD + k * DV + vb;
#pragma unroll
  for (int g = 0; g < 4; ++g) {
    float4 xv = *reinterpret_cast<const float4*>(xr + k * DV + vb + g * 4);
    float dx = r4[g].x - xv.x, dy = r4[g].y - xv.y;
    float dz = r4[g].z - xv.z, dw = r4[g].w - xv.w;
    m = fmaf(dx, dx, m); m = fmaf(dy, dy, m);
    m = fmaf(dz, dz, m); m = fmaf(dw, dw, m);
    *reinterpret_cast<float4*>(ro + g * 4) = r4[g];
  }
  red[t] = m;
  __syncthreads();
  for (int s2 = 128; s2 > 0; s2 >>= 1) {
    if (t < s2) red[t] += red[t + s2];
    __syncthreads();
  }
  if (t == 0) msepart[b] = red[0];
}

__global__ void k_mse(const float* __restrict__ msepart, float* __restrict__ out) {
  __shared__ float red[256];
  int t = threadIdx.x;
  float s = 0.f;
  for (int i = t; i < BATCH; i += 256) s += msepart[i];
  red[t] = s;
  __syncthreads();
  for (int k = 128; k > 0; k >>= 1) {
    if (t < k) red[t] += red[t + k];
    __syncthreads();
  }
  if (t == 0) out[0] = red[0] / (float)((size_t)BATCH * DD);
}

extern "C" void kernel_launch(void* const* d_in, const int* in_sizes, int n_in,
                              void* d_out, int out_size, void* d_ws, size_t ws_size,
                              hipStream_t stream) {
  const float* x    = (const float*)d_in[0];
  const float* Venc = (const float*)d_in[1];
  const float* Wenc = (const float*)d_in[2];
  const float* benc = (const float*)d_in[3];
  const float* Vdec = (const float*)d_in[4];
  const float* Wdec = (const float*)d_in[5];
  const float* bias = (const float*)d_in[6];

  float* out = (float*)d_out;
  float* recon  = out;                                   // [1024, 4096]
  float* coeffs = out + (size_t)BATCH * DD;              // [1024, 32768]
  float* mse    = coeffs + (size_t)BATCH * NFEAT;        // [1]

  char* wsp = (char*)d_ws;
  unsigned char* xb8 = (unsigned char*)wsp;   wsp += (size_t)BATCH * DD;
  unsigned char* Menc8 = (unsigned char*)wsp; wsp += (size_t)NFEAT * DD;
  int* cand_idx = (int*)wsp;                  wsp += (size_t)BATCH * CAND_CAP * sizeof(int);
  int* cand_cnt = (int*)wsp;                  wsp += (size_t)BATCH * sizeof(int);
  float* msepart = (float*)wsp;               wsp += (size_t)BATCH * sizeof(float);
  bf16* pre = (bf16*)wsp;                     wsp += (size_t)BATCH * NFEAT * sizeof(bf16);

  hipFuncSetAttribute((const void*)k_gemm, hipFuncAttributeMaxDynamicSharedMemorySize,
                      GEMM_LDS);

  k_convert_x<<<(BATCH * DD) / (256 * 16), 256, 0, stream>>>(x, xb8, BATCH * DD);
  k_build_menc<<<NFEAT, 256, 0, stream>>>(Venc, Wenc, Menc8);
  k_gemm<<<(BATCH / BM) * (NFEAT / BN), 512, GEMM_LDS, stream>>>(xb8, Menc8, benc, pre);
  k_topk<<<BATCH, 256, 0, stream>>>((const unsigned short*)pre, cand_idx, cand_cnt, coeffs);
  k_refine<<<BATCH, 256, 0, stream>>>(x, Venc, Wenc, benc, Vdec, Wdec, bias,
                                      cand_idx, cand_cnt, recon, coeffs, msepart);
  k_mse<<<1, 256, 0, stream>>>(msepart, mse);
}

// Round 10
// 296.265 us; speedup vs baseline: 1.0655x; 1.0655x over previous
//
#include <hip/hip_runtime.h>
#include <hip/hip_bf16.h>
#include <hip/hip_fp8.h>
#include <stdint.h>

#define NFEAT 32768
#define BATCH 1024
#define DK 64
#define DV 64
#define DD 4096
#define KSEL 32
#define CAND_CAP 512
#define CAND_TARGET 128

using bf16 = __bf16;
using f32x4 = __attribute__((ext_vector_type(4))) float;
using f32x16 = __attribute__((ext_vector_type(16))) float;
using i32x4 = __attribute__((ext_vector_type(4))) int;
using i32x8 = __attribute__((ext_vector_type(8))) int;

__device__ __forceinline__ void gload_lds16(const void* g, void* l) {
  __builtin_amdgcn_global_load_lds((const __attribute__((address_space(1))) void*)g,
                                   (__attribute__((address_space(3))) void*)l,
                                   16, 0, 0);
}

__device__ inline unsigned mono16(unsigned u) {
  return (u & 0x8000u) ? ((~u) & 0xFFFFu) : (u | 0x8000u);
}

// Tiled fp8 layout: chunk = (r>>5)*128 + (c>>5); within-chunk offset for M[r][c]:
//   o = ((c>>4)&1)*512 + (r&31)*16 + (c&15)
// (byte-identical to the round-9 verified fragment-major LDS chunk content).

// ---------------- x -> fp8 e4m3, tiled ----------------
// grid 256: rb = bid>>3 (32-row block), kg in [(bid&7)*16, +16). 256 threads:
// row=(t&127)>>2, cin=((t>>7)<<4)+((t&3)<<2); write 4B at chunk offset t*4.
__global__ void k_convert_x(const float* __restrict__ x, unsigned char* __restrict__ xb) {
  int t = threadIdx.x;
  int rb = blockIdx.x >> 3;
  int kg0 = (blockIdx.x & 7) * 16;
  int row = (t & 127) >> 2;
  int cin = ((t >> 7) << 4) + ((t & 3) << 2);
  const float* xrow = x + ((size_t)rb * 32 + row) * DD;
  for (int kg = kg0; kg < kg0 + 16; ++kg) {
    float4 v = *reinterpret_cast<const float4*>(xrow + kg * 32 + cin);
    union { unsigned char b[4]; unsigned u; } o;
    o.b[0] = __hip_fp8_e4m3(v.x).__x;
    o.b[1] = __hip_fp8_e4m3(v.y).__x;
    o.b[2] = __hip_fp8_e4m3(v.z).__x;
    o.b[3] = __hip_fp8_e4m3(v.w).__x;
    *reinterpret_cast<unsigned*>(xb + (((size_t)rb * 128 + kg) << 10) + t * 4) = o.u;
  }
}

// ---------------- M_enc fp8 tiled: 16 * V_enc[i][k] * W_enc[i][v] ----------------
// grid 1024 (32 features each), 128 chunk-iters; chunk kg: k = kg>>1 (constant),
// v = (kg&1)*32 + colbyte. Per-thread W float4s preloaded; stores 1KB/wave coalesced.
__global__ void k_build_menc(const float* __restrict__ Venc, const float* __restrict__ Wenc,
                             unsigned char* __restrict__ Menc) {
  int t = threadIdx.x;
  int rb = blockIdx.x;
  int row = (t & 127) >> 2;
  int cin = ((t >> 7) << 4) + ((t & 3) << 2);
  size_t rowg = (size_t)rb * 32 + row;
  const float* vrow = Venc + rowg * DK;
  float4 w0 = *reinterpret_cast<const float4*>(Wenc + rowg * DV + cin);
  float4 w1 = *reinterpret_cast<const float4*>(Wenc + rowg * DV + 32 + cin);
  unsigned char* base = Menc + ((size_t)rb << 17);  // rb * 128 KiB
#pragma unroll 4
  for (int kg = 0; kg < 128; ++kg) {
    float vk = 16.0f * vrow[kg >> 1];
    float4 w = (kg & 1) ? w1 : w0;
    union { unsigned char b[4]; unsigned u; } o;
    o.b[0] = __hip_fp8_e4m3(vk * w.x).__x;
    o.b[1] = __hip_fp8_e4m3(vk * w.y).__x;
    o.b[2] = __hip_fp8_e4m3(vk * w.z).__x;
    o.b[3] = __hip_fp8_e4m3(vk * w.w).__x;
    *reinterpret_cast<unsigned*>(base + (kg << 10) + t * 4) = o.u;
  }
}

// ---------------- GEMM: pre = bf16((x8 @ Menc8^T)/16 + b_enc), MX-fp8 MFMA ----------------
// 256x256 tile, BK=128 bytes, 8 waves (2M x 4N), double-buffered LDS, snake schedule
// (same barrier/vmcnt proof as rounds 6-9). Fragment-major LDS (round-9 verified) +
// chunk-major global staging: each gload_lds reads 1 KiB contiguous (src = base + lane*16).
#define BM 256
#define BN 256
#define BKB 128               // K-bytes per tile
#define NT (DD / BKB)         // 32 K-tiles
#define ABUF 32768            // 32 chunks
#define BUFSZ 65536           // A + B per K-tile
#define GEMM_LDS (2 * BUFSZ)  // 128 KiB

// chunk c: b32 = c>>2 (32-row block), kg = c&3 (32-byte k-group)
__device__ __forceinline__ void stage_chunk(const unsigned char* __restrict__ G, size_t r32base,
                                            int kg0, int c, int lane, char* dstbase) {
  const unsigned char* src = G + (((r32base + (c >> 2)) * 128 + kg0 + (c & 3)) << 10) + lane * 16;
  gload_lds16(src, dstbase + c * 1024);
}

__device__ __forceinline__ i32x8 frag_ld8(const char* base, int chunk, int lane) {
  const char* p = base + chunk * 1024 + (lane & 31) * 16;
  i32x4 lo = *reinterpret_cast<const i32x4*>(p);
  i32x4 hi = *reinterpret_cast<const i32x4*>(p + 512);
  i32x8 r;
  r[0] = lo[0]; r[1] = lo[1]; r[2] = lo[2]; r[3] = lo[3];
  r[4] = hi[0]; r[5] = hi[1]; r[6] = hi[2]; r[7] = hi[3];
  return r;
}

// half-tile chunk maps (idx = wave*2 + j, 0..15) — as verified in round 9
__device__ __forceinline__ int chA(int half, int idx) {
  int g = idx >> 2, kg = idx & 3;
  int mb32 = (g & 1) + ((g >> 1) << 2) + half * 2;
  return mb32 * 4 + kg;
}
__device__ __forceinline__ int chB(int half, int idx) {
  int nb32 = ((idx >> 2) << 1) + half;
  return nb32 * 4 + (idx & 3);
}

#define LD_A(H)                                                                     \
  _Pragma("unroll") for (int mb = 0; mb < 2; ++mb)                                  \
  _Pragma("unroll") for (int kh = 0; kh < 2; ++kh)                                  \
    afr[mb][kh] = frag_ld8(cur, (wr * 4 + (H) * 2 + mb) * 4 + kh * 2 + (lane >> 5), lane);

#define LD_B(H)                                                                     \
  _Pragma("unroll") for (int kh = 0; kh < 2; ++kh)                                  \
    bfr[(H)][kh] = frag_ld8(cur + ABUF, (wc * 2 + (H)) * 4 + kh * 2 + (lane >> 5), lane);

#define ST_A(HALF, KT)                                                              \
  stage_chunk(A, ar32, (KT) * 4, chA(HALF, wave * 2), lane, nxt);                   \
  stage_chunk(A, ar32, (KT) * 4, chA(HALF, wave * 2 + 1), lane, nxt);

#define ST_B(HALF, KT)                                                              \
  stage_chunk(Bt, br32, (KT) * 4, chB(HALF, wave * 2), lane, nxt + ABUF);           \
  stage_chunk(Bt, br32, (KT) * 4, chB(HALF, wave * 2 + 1), lane, nxt + ABUF);

#define MFMA_Q(MH, NB)                                                              \
  asm volatile("s_waitcnt lgkmcnt(0)" ::: "memory");                                \
  __builtin_amdgcn_sched_barrier(0);                                                \
  __builtin_amdgcn_s_setprio(1);                                                    \
  _Pragma("unroll") for (int mb = 0; mb < 2; ++mb)                                  \
  _Pragma("unroll") for (int kh = 0; kh < 2; ++kh)                                  \
    acc[(MH) * 2 + mb][NB] = __builtin_amdgcn_mfma_scale_f32_32x32x64_f8f6f4(       \
        afr[mb][kh], bfr[NB][kh], acc[(MH) * 2 + mb][NB], 0, 0, 0, 0x7F, 0, 0x7F);  \
  __builtin_amdgcn_s_setprio(0);

#define VMC(N) asm volatile("s_waitcnt vmcnt(" #N ")" ::: "memory");
#define LGKM0 asm volatile("s_waitcnt lgkmcnt(0)" ::: "memory");
#define BARR                                                                        \
  asm volatile("s_barrier" ::: "memory");                                           \
  __builtin_amdgcn_sched_barrier(0);

__global__ __launch_bounds__(512, 2)
void k_gemm(const unsigned char* __restrict__ A, const unsigned char* __restrict__ Bt,
            const float* __restrict__ benc, bf16* __restrict__ C) {
  extern __shared__ char lds[];
  int tid = threadIdx.x;
  int wave = tid >> 6;
  int lane = tid & 63;
  int wr = wave >> 2;          // 0..1, 128 rows each
  int wc = wave & 3;           // 0..3, 64 cols each

  // XCD-grouped bijective remap (512 blocks, 512%8==0)
  int d = blockIdx.x;                  // 0..511
  int lw = (d & 7) * 64 + (d >> 3);
  int q = lw >> 2;                     // col panel 0..127
  int p = lw & 3;                      // row block 0..3
  size_t brow = (size_t)p * BM;
  size_t bcol = (size_t)q * BN;
  size_t ar32 = brow >> 5;
  size_t br32 = bcol >> 5;

  f32x16 acc[4][2] = {};
  i32x8 afr[2][2];
  i32x8 bfr[2][2];

  // prologue: stage tile 0 (order B0,A0,B1,A1); publish B0,A0; barrier.
  {
    char* nxt = lds;
    ST_B(0, 0) ST_A(0, 0) ST_B(1, 0) ST_A(1, 0)
  }
  VMC(4)
  BARR

#pragma unroll 1
  for (int u = 0; u < NT - 1; ++u) {
    char* cur = lds + (u & 1) * BUFSZ;
    char* nxt = lds + ((u + 1) & 1) * BUFSZ;
    int k1 = u + 1;
    // q0: read A-h0, B-n0; stage B0(u+1); VMC(4) publishes B1(u) for q1
    LD_A(0) LD_B(0)
    ST_B(0, k1)
    VMC(4)
    BARR
    MFMA_Q(0, 0)
    // q1: read B-n1; stage A0(u+1); VMC(4) publishes A1(u) for q23
    LD_B(1)
    ST_A(0, k1)
    VMC(4)
    BARR
    MFMA_Q(0, 1)
    // q23: read A-h1; stage B1,A1(u+1); VMC(4) publishes B0,A0(u+1); lgkm drained pre-barrier
    LD_A(1)
    ST_B(1, k1) ST_A(1, k1)
    VMC(4)
    LGKM0
    BARR
    MFMA_Q(1, 1)
    MFMA_Q(1, 0)
  }

  // tail tile NT-1 (no staging); entry outstanding: B1(L),A1(L)
  {
    char* cur = lds + ((NT - 1) & 1) * BUFSZ;
    LD_A(0) LD_B(0)
    VMC(2)
    BARR
    MFMA_Q(0, 0)
    LD_B(1)
    VMC(0)
    BARR
    MFMA_Q(0, 1)
    LD_A(1)
    LGKM0
    BARR
    MFMA_Q(1, 1)
    MFMA_Q(1, 0)
  }

  // epilogue: 32x32 C/D layout col=lane&31, row=(reg&3)+8*(reg>>2)+4*(lane>>5); descale 1/16
#pragma unroll
  for (int nb = 0; nb < 2; ++nb) {
    size_t col = bcol + wc * 64 + nb * 32 + (lane & 31);
    float be = benc[col];
#pragma unroll
    for (int MB = 0; MB < 4; ++MB) {
      size_t row0 = brow + wr * 128 + MB * 32 + ((lane >> 5) << 2);
#pragma unroll
      for (int reg = 0; reg < 16; ++reg) {
        size_t row = row0 + (reg & 3) + ((reg >> 2) << 3);
        C[row * NFEAT + col] = (bf16)(acc[MB][nb][reg] * 0.0625f + be);
      }
    }
  }
}

// ---------------- candidate extraction from bf16 pre + zero coeffs row ----------------
__global__ void k_topk(const unsigned short* __restrict__ pre, int* __restrict__ cand_idx,
                       int* __restrict__ cand_cnt, float* __restrict__ coeffs) {
  __shared__ int hist[8192];   // 13-bit bins of 16-bit monotonic code
  __shared__ int csum[256];
  __shared__ int sBstar;
  __shared__ int scount;
  int b = blockIdx.x;
  int t = threadIdx.x;
  const unsigned short* row = pre + (size_t)b * NFEAT;
  for (int i = t; i < 8192; i += 256) hist[i] = 0;
  if (t == 0) scount = 0;
  __syncthreads();

  for (int i = (t << 3); i < NFEAT; i += 2048) {
    uint4 v = *reinterpret_cast<const uint4*>(row + i);
#pragma unroll
    for (int j = 0; j < 4; ++j) {
      unsigned w = (&v.x)[j];
      atomicAdd(&hist[mono16(w & 0xFFFFu) >> 3], 1);
      atomicAdd(&hist[mono16(w >> 16) >> 3], 1);
    }
  }
  __syncthreads();

  int s = 0;
  for (int i = 0; i < 32; ++i) s += hist[t * 32 + i];
  csum[t] = s;
  __syncthreads();
  int suff = 0;
  for (int j = t + 1; j < 256; ++j) suff += csum[j];
  if (suff < CAND_TARGET && suff + s >= CAND_TARGET) {
    int acc = suff;
    int bstar = t * 32;
    for (int i = 31; i >= 0; --i) {
      acc += hist[t * 32 + i];
      if (acc >= CAND_TARGET) { bstar = t * 32 + i; break; }
    }
    sBstar = bstar;
  }
  __syncthreads();
  int Bstar = sBstar;
  int* cidx = cand_idx + b * CAND_CAP;

  for (int i = (t << 3); i < NFEAT; i += 2048) {
    uint4 v = *reinterpret_cast<const uint4*>(row + i);
#pragma unroll
    for (int j = 0; j < 4; ++j) {
      unsigned w = (&v.x)[j];
      int b0 = (int)(mono16(w & 0xFFFFu) >> 3);
      int b1 = (int)(mono16(w >> 16) >> 3);
      if (b0 >= Bstar) { int p2 = atomicAdd(&scount, 1); if (p2 < CAND_CAP) cidx[p2] = i + j * 2; }
      if (b1 >= Bstar) { int p2 = atomicAdd(&scount, 1); if (p2 < CAND_CAP) cidx[p2] = i + j * 2 + 1; }
    }
  }
  __syncthreads();
  if (t == 0) cand_cnt[b] = (scount < CAND_CAP) ? scount : CAND_CAP;

  // zero this row of coeffs (refine scatters after this kernel)
  float* crow = coeffs + (size_t)b * NFEAT;
  float4 z4 = {0.f, 0.f, 0.f, 0.f};
  for (int i = (t << 2); i < NFEAT; i += 1024)
    *reinterpret_cast<float4*>(crow + i) = z4;
}

// ---------------- fp32 refine + exact top-32 + scatter + decode + mse partial ----------------
__global__ void k_refine(const float* __restrict__ x,
                         const float* __restrict__ Venc,
                         const float* __restrict__ Wenc,
                         const float* __restrict__ benc,
                         const float* __restrict__ Vdec,
                         const float* __restrict__ Wdec,
                         const float* __restrict__ bias,
                         const int* __restrict__ cand_idx,
                         const int* __restrict__ cand_cnt,
                         float* __restrict__ recon,
                         float* __restrict__ coeffs,
                         float* __restrict__ msepart) {
  __shared__ float rval[CAND_CAP];
  __shared__ int ridx[CAND_CAP];
  __shared__ float selv[KSEL];
  __shared__ int seli[KSEL];
  __shared__ float Vd[KSEL][DK];
  __shared__ float Wd[KSEL][DV];
  __shared__ float red[256];

  int b = blockIdx.x;
  int t = threadIdx.x;
  int wave = t >> 6;
  int lane = t & 63;

  const float* xr = x + (size_t)b * DD;

  // per-lane register cache of x: xreg[kk] = x[b][kk][lane] (lane = v)
  float xreg[DK];
#pragma unroll
  for (int kk = 0; kk < DK; ++kk)
    xreg[kk] = xr[kk * DV + lane];

  int c = cand_cnt[b];
  if (c > CAND_CAP) c = CAND_CAP;
  for (int i = t; i < c; i += 256) ridx[i] = cand_idx[b * CAND_CAP + i];
  __syncthreads();

  // exact fp32 pre per candidate: V row via SGPR (uniform), x in regs, W coalesced
  for (int j = wave; j < c; j += 4) {
    int fi = __builtin_amdgcn_readfirstlane(ridx[j]);
    const float* vr = Venc + (size_t)fi * DK;
    float w = Wenc[(size_t)fi * DV + lane];
    float a0 = 0.f, a1 = 0.f, a2 = 0.f, a3 = 0.f;
#pragma unroll
    for (int kk = 0; kk < DK; kk += 4) {
      a0 = fmaf(xreg[kk + 0], vr[kk + 0], a0);
      a1 = fmaf(xreg[kk + 1], vr[kk + 1], a1);
      a2 = fmaf(xreg[kk + 2], vr[kk + 2], a2);
      a3 = fmaf(xreg[kk + 3], vr[kk + 3], a3);
    }
    float p2 = ((a0 + a1) + (a2 + a3)) * w;
#pragma unroll
    for (int off = 1; off < 64; off <<= 1) p2 += __shfl_xor(p2, off);
    if (lane == 0) rval[j] = p2 + benc[fi];
  }
  __syncthreads();

  // exact rank among candidates (tie-break: lower feature index first, matches np)
  for (int t2 = t; t2 < c; t2 += 256) {
    float v = rval[t2];
    int fi = ridx[t2];
    int rank = 0;
    for (int j = 0; j < c; ++j) {
      float vj = rval[j];
      if (vj > v || (vj == v && ridx[j] < fi)) ++rank;
    }
    if (rank < KSEL) { selv[rank] = v; seli[rank] = fi; }
  }
  __syncthreads();

  if (t < KSEL) {
    float v = fmaxf(selv[t], 0.f);
    selv[t] = v;
    coeffs[(size_t)b * NFEAT + seli[t]] = v;
  }
  __syncthreads();

  for (int i = t; i < KSEL * DK; i += 256) {
    int s = i >> 6, e = i & 63;
    Vd[s][e] = Vdec[(size_t)seli[s] * DK + e];
    Wd[s][e] = Wdec[(size_t)seli[s] * DV + e];
  }
  __syncthreads();

  // decode: thread owns 16 contiguous recon elems; Wd consumed as float4
  int k = t >> 2;
  int vb = (t & 3) << 4;
  float4 r4[4];
#pragma unroll
  for (int g = 0; g < 4; ++g)
    r4[g] = *reinterpret_cast<const float4*>(bias + k * DV + vb + g * 4);
#pragma unroll
  for (int s = 0; s < KSEL; ++s) {
    float a = selv[s] * Vd[s][k];
    const float4* wrow = reinterpret_cast<const float4*>(&Wd[s][vb]);
#pragma unroll
    for (int g = 0; g < 4; ++g) {
      float4 wv = wrow[g];
      r4[g].x = fmaf(a, wv.x, r4[g].x);
      r4[g].y = fmaf(a, wv.y, r4[g].y);
      r4[g].z = fmaf(a, wv.z, r4[g].z);
      r4[g].w = fmaf(a, wv.w, r4[g].w);
    }
  }
  float m = 0.f;
  float* ro = recon + (size_t)b * DD + k * DV + vb;
#pragma unroll
  for (int g = 0; g < 4; ++g) {
    float4 xv = *reinterpret_cast<const float4*>(xr + k * DV + vb + g * 4);
    float dx = r4[g].x - xv.x, dy = r4[g].y - xv.y;
    float dz = r4[g].z - xv.z, dw = r4[g].w - xv.w;
    m = fmaf(dx, dx, m); m = fmaf(dy, dy, m);
    m = fmaf(dz, dz, m); m = fmaf(dw, dw, m);
    *reinterpret_cast<float4*>(ro + g * 4) = r4[g];
  }
  red[t] = m;
  __syncthreads();
  for (int s2 = 128; s2 > 0; s2 >>= 1) {
    if (t < s2) red[t] += red[t + s2];
    __syncthreads();
  }
  if (t == 0) msepart[b] = red[0];
}

__global__ void k_mse(const float* __restrict__ msepart, float* __restrict__ out) {
  __shared__ float red[256];
  int t = threadIdx.x;
  float s = 0.f;
  for (int i = t; i < BATCH; i += 256) s += msepart[i];
  red[t] = s;
  __syncthreads();
  for (int k = 128; k > 0; k >>= 1) {
    if (t < k) red[t] += red[t + k];
    __syncthreads();
  }
  if (t == 0) out[0] = red[0] / (float)((size_t)BATCH * DD);
}

extern "C" void kernel_launch(void* const* d_in, const int* in_sizes, int n_in,
                              void* d_out, int out_size, void* d_ws, size_t ws_size,
                              hipStream_t stream) {
  const float* x    = (const float*)d_in[0];
  const float* Venc = (const float*)d_in[1];
  const float* Wenc = (const float*)d_in[2];
  const float* benc = (const float*)d_in[3];
  const float* Vdec = (const float*)d_in[4];
  const float* Wdec = (const float*)d_in[5];
  const float* bias = (const float*)d_in[6];

  float* out = (float*)d_out;
  float* recon  = out;                                   // [1024, 4096]
  float* coeffs = out + (size_t)BATCH * DD;              // [1024, 32768]
  float* mse    = coeffs + (size_t)BATCH * NFEAT;        // [1]

  char* wsp = (char*)d_ws;
  unsigned char* xb8 = (unsigned char*)wsp;   wsp += (size_t)BATCH * DD;
  unsigned char* Menc8 = (unsigned char*)wsp; wsp += (size_t)NFEAT * DD;
  int* cand_idx = (int*)wsp;                  wsp += (size_t)BATCH * CAND_CAP * sizeof(int);
  int* cand_cnt = (int*)wsp;                  wsp += (size_t)BATCH * sizeof(int);
  float* msepart = (float*)wsp;               wsp += (size_t)BATCH * sizeof(float);
  bf16* pre = (bf16*)wsp;                     wsp += (size_t)BATCH * NFEAT * sizeof(bf16);

  hipFuncSetAttribute((const void*)k_gemm, hipFuncAttributeMaxDynamicSharedMemorySize,
                      GEMM_LDS);

  k_convert_x<<<256, 256, 0, stream>>>(x, xb8);
  k_build_menc<<<NFEAT / 32, 256, 0, stream>>>(Venc, Wenc, Menc8);
  k_gemm<<<(BATCH / BM) * (NFEAT / BN), 512, GEMM_LDS, stream>>>(xb8, Menc8, benc, pre);
  k_topk<<<BATCH, 256, 0, stream>>>((const unsigned short*)pre, cand_idx, cand_cnt, coeffs);
  k_refine<<<BATCH, 256, 0, stream>>>(x, Venc, Wenc, benc, Vdec, Wdec, bias,
                                      cand_idx, cand_cnt, recon, coeffs, msepart);
  k_mse<<<1, 256, 0, stream>>>(msepart, mse);
}